// Round 16
// baseline (340.230 us; speedup 1.0000x reference)
//
#include <hip/hip_runtime.h>
#include <hip/hip_bf16.h>
#include <hip/hip_fp16.h>
#include <math.h>

#define LQ 24480
#define QSTRIDE 1408   // qout row stride (11 x 128 col-blocks)

typedef short bf16x8 __attribute__((ext_vector_type(8)));   // 8 bf16 = 16B
typedef float f32x4 __attribute__((ext_vector_type(4)));
typedef float f32x4v __attribute__((ext_vector_type(4)));

static __device__ __forceinline__ float bf2f(ushort u) {
    union { unsigned int i; float f; } v; v.i = ((unsigned int)u) << 16; return v.f;
}
static __device__ __forceinline__ ushort f2bf(float f) {
    __hip_bfloat16 h = __float2bfloat16(f);
    return *reinterpret_cast<ushort*>(&h);
}
static __device__ __forceinline__ ushort f2h(float f) {
    __half h = __float2half(f);
    return *reinterpret_cast<ushort*>(&h);
}
static __device__ __forceinline__ float u2f_lo(unsigned int u) {
    union { unsigned int i; float f; } v; v.i = u << 16; return v.f;
}
static __device__ __forceinline__ float u2f_hi(unsigned int u) {
    union { unsigned int i; float f; } v; v.i = u & 0xffff0000u; return v.f;
}
// packed f16 FMA, weight broadcast from lo half of w
static __device__ __forceinline__ void pkf16_lo(unsigned& acc, unsigned v, unsigned w) {
    asm("v_pk_fma_f16 %0, %1, %2, %0 op_sel:[0,0,0] op_sel_hi:[1,0,1]"
        : "+v"(acc) : "v"(v), "v"(w));
}
// weight broadcast from hi half of w
static __device__ __forceinline__ void pkf16_hi(unsigned& acc, unsigned v, unsigned w) {
    asm("v_pk_fma_f16 %0, %1, %2, %0 op_sel:[0,1,0] op_sel_hi:[1,1,1]"
        : "+v"(acc) : "v"(v), "v"(w));
}
// async global -> LDS, 16B per lane (wave-uniform LDS base + lane*16)
static __device__ __forceinline__ void gload16(const ushort* g, ushort* l) {
    __builtin_amdgcn_global_load_lds(
        (const __attribute__((address_space(1))) void*)g,
        (__attribute__((address_space(3))) void*)l,
        16, 0, 0);
}

// ---------------------------------------------------------------------------
// LDS-staged GEMM body: block 128x128, BK=32, double-buffered via
// global_load_lds (async DMA, no VGPR round-trip, no ds_write).
// LDS layout per buffer (linear, 512 x 16B units): unit = kblk*128 + slot.
// A: slot = row. B: slot = (c&3)*32 + (c>>2) -- achieved by pre-swizzling the
// per-lane GLOBAL source (c = ((s&31)<<2)|(s>>5)) while LDS stays linear.
// Fragment reads are lane-consecutive 16B -> conflict-free ds_read_b128.
// Column-permuted epilogue: thread owns 4 consecutive cols, packed 8B stores.
// ---------------------------------------------------------------------------
template <int RELU, int F16OUT>
static __device__ __forceinline__ void gemm_lds128(
    const ushort* __restrict__ A, const ushort* __restrict__ W,
    const float* __restrict__ bias, ushort* __restrict__ Cb,
    int M, int N, int K, int bm, int bn,
    ushort* As, ushort* Bs, int tid)
{
    const int w = tid >> 6, lane = tid & 63;
    const int wm = w >> 1, wn = w & 1;
    const int r = lane & 15, kblk4 = lane >> 4;

    // staging: wave w owns kblk=w; instr0 rows/slots 0..63, instr1 64..127.
    const ushort* gA0 = A + (size_t)(bm + lane) * K + w * 8;
    const ushort* gA1 = A + (size_t)(bm + 64 + lane) * K + w * 8;
    const int cB0 = ((lane & 31) << 2) | (lane >> 5);
    const int cB1 = (((64 + lane) & 31) << 2) | ((64 + lane) >> 5);
    const ushort* gB0 = W + (size_t)(bn + cB0) * K + w * 8;
    const ushort* gB1 = W + (size_t)(bn + cB1) * K + w * 8;
    ushort* lA0 = As + w * 1024;  ushort* lA1 = lA0 + 512;
    ushort* lB0 = Bs + w * 1024;  ushort* lB1 = lB0 + 512;

    f32x4 acc[4][4] = {};

    // prologue: stage k-step 0 into buffer 0
    gload16(gA0, lA0); gload16(gA1, lA1);
    gload16(gB0, lB0); gload16(gB1, lB1);

    const int NK = K >> 5;
    int buf = 0;
    for (int kt = 0; kt < NK; ++kt) {
        __syncthreads();                 // drains outstanding loads into buf
        if (kt + 1 < NK) {               // async-stage next step -> other buf
            int ko = (kt + 1) * 32;
            int bo = (buf ^ 1) * 4096;
            gload16(gA0 + ko, lA0 + bo); gload16(gA1 + ko, lA1 + bo);
            gload16(gB0 + ko, lB0 + bo); gload16(gB1 + ko, lB1 + bo);
        }
        const ushort* Ab = As + buf * 4096;
        const ushort* Bb = Bs + buf * 4096;
        bf16x8 a[4], b[4];
#pragma unroll
        for (int i = 0; i < 4; ++i)
            a[i] = *(const bf16x8*)(Ab + (kblk4 * 128 + wm * 64 + i * 16 + r) * 8);
#pragma unroll
        for (int j = 0; j < 4; ++j)
            b[j] = *(const bf16x8*)(Bb + (kblk4 * 128 + j * 32 + wn * 16 + r) * 8);
#pragma unroll
        for (int i = 0; i < 4; ++i)
#pragma unroll
            for (int j = 0; j < 4; ++j)
                acc[i][j] = __builtin_amdgcn_mfma_f32_16x16x32_bf16(a[i], b[j], acc[i][j], 0, 0, 0);
        buf ^= 1;
    }

    const int c0 = bn + wn * 64 + r * 4;
    if (c0 >= N) return;
    const float4 bv = *(const float4*)(bias + c0);
    const int orow = kblk4 * 4;
#pragma unroll
    for (int i = 0; i < 4; ++i)
#pragma unroll
        for (int t = 0; t < 4; ++t) {
            int rr = bm + wm * 64 + i * 16 + orow + t;
            if (rr < M) {
                float v0 = acc[i][0][t] + bv.x;
                float v1 = acc[i][1][t] + bv.y;
                float v2 = acc[i][2][t] + bv.z;
                float v3 = acc[i][3][t] + bv.w;
                if (RELU) {
                    v0 = fmaxf(v0, 0.f); v1 = fmaxf(v1, 0.f);
                    v2 = fmaxf(v2, 0.f); v3 = fmaxf(v3, 0.f);
                }
                uint2 pk;
                if (F16OUT) {
                    pk.x = (unsigned)f2h(v0) | ((unsigned)f2h(v1) << 16);
                    pk.y = (unsigned)f2h(v2) | ((unsigned)f2h(v3) << 16);
                } else {
                    pk.x = (unsigned)f2bf(v0) | ((unsigned)f2bf(v1) << 16);
                    pk.y = (unsigned)f2bf(v2) | ((unsigned)f2bf(v3) << 16);
                }
                *(uint2*)(Cb + (size_t)rr * N + c0) = pk;
            }
        }
}

// Fused value-proj (fp16 out, N=256) + q-proj (bf16 out, N=1408 padded).
__global__ __launch_bounds__(256) void gemm_valq(
    const ushort* __restrict__ srcb, const ushort* __restrict__ qb,
    const ushort* __restrict__ Wv, const ushort* __restrict__ Wq,
    const float* __restrict__ b_val, const float* __restrict__ bq,
    ushort* __restrict__ valh, ushort* __restrict__ qout)
{
    __shared__ ushort As[2 * 4096];
    __shared__ ushort Bs[2 * 4096];
    const int bx = blockIdx.x;   // 0..12
    if (bx < 2) {
        gemm_lds128<0, 1>(srcb, Wv, b_val, valh, LQ, 256, 256,
                          blockIdx.y * 128, bx * 128, As, Bs, threadIdx.x);
    } else {
        gemm_lds128<0, 0>(qb, Wq, bq, qout, LQ, QSTRIDE, 256,
                          blockIdx.y * 128, (bx - 2) * 128, As, Bs, threadIdx.x);
    }
}

// ff1: relu, bf16 out, N=1024
__global__ __launch_bounds__(256) void gemm_ff1(
    const ushort* __restrict__ A, const ushort* __restrict__ W,
    const float* __restrict__ bias, ushort* __restrict__ Cb)
{
    __shared__ ushort As[2 * 4096];
    __shared__ ushort Bs[2 * 4096];
    gemm_lds128<1, 0>(A, W, bias, Cb, LQ, 1024, 256,
                      blockIdx.y * 128, blockIdx.x * 128, As, Bs, threadIdx.x);
}

// ---------------------------------------------------------------------------
// Fused GEMM (N=256) + residual + LayerNorm (direct-from-global fragments).
// ---------------------------------------------------------------------------
template <int RES16, int WF32, int WBF16>
__global__ __launch_bounds__(256) void gemm_ln(
    const ushort* __restrict__ A, const ushort* __restrict__ W,
    const float* __restrict__ bias, const void* __restrict__ res,
    const float* __restrict__ g, const float* __restrict__ be,
    float* __restrict__ outF, ushort* __restrict__ outB,
    int M, int K)
{
    const int wave = threadIdx.x >> 6;
    const int lane = threadIdx.x & 63;
    const int r = lane & 15;
    const int kblk = lane >> 4;
    const int bm = blockIdx.x * 128;
    const int c0 = r * 16;

    f32x4 acc[2][16] = {};

    int row0 = bm + wave * 32 + r;
    int row1 = row0 + 16;
    row0 = min(row0, M - 1);
    row1 = min(row1, M - 1);
    const ushort* ap0 = A + (size_t)row0 * K + kblk * 8;
    const ushort* ap1 = A + (size_t)row1 * K + kblk * 8;
    const ushort* wp  = W + (size_t)c0 * K + kblk * 8;

#pragma unroll 2
    for (int k = 0; k < K; k += 32) {
        bf16x8 a0 = *(const bf16x8*)(ap0 + k);
        bf16x8 a1 = *(const bf16x8*)(ap1 + k);
#pragma unroll
        for (int ni = 0; ni < 16; ++ni) {
            bf16x8 b = *(const bf16x8*)(wp + (size_t)ni * K + k);
            acc[0][ni] = __builtin_amdgcn_mfma_f32_16x16x32_bf16(a0, b, acc[0][ni], 0, 0, 0);
            acc[1][ni] = __builtin_amdgcn_mfma_f32_16x16x32_bf16(a1, b, acc[1][ni], 0, 0, 0);
        }
    }

    const int orow = kblk * 4;

    float bv[16];
#pragma unroll
    for (int q = 0; q < 4; ++q)
        *(float4*)(bv + q * 4) = *(const float4*)(bias + c0 + q * 4);

    float mean_[2][4], rstd_[2][4];
#pragma unroll
    for (int mi = 0; mi < 2; ++mi)
#pragma unroll
        for (int j = 0; j < 4; ++j) {
            int rr = bm + wave * 32 + mi * 16 + orow + j;
            int rl = min(rr, M - 1);
            float rv[16];
            if (RES16) {
                const ushort* r16 = (const ushort*)res + (size_t)rl * 256 + c0;
                uint4 ra = *(const uint4*)r16;
                uint4 rb = *(const uint4*)(r16 + 8);
                unsigned ru[8] = {ra.x, ra.y, ra.z, ra.w, rb.x, rb.y, rb.z, rb.w};
#pragma unroll
                for (int b = 0; b < 8; ++b) {
                    rv[2 * b]     = u2f_lo(ru[b]);
                    rv[2 * b + 1] = u2f_hi(ru[b]);
                }
            } else {
                const float* rp = (const float*)res + (size_t)rl * 256 + c0;
#pragma unroll
                for (int q = 0; q < 4; ++q)
                    *(float4*)(rv + q * 4) = *(const float4*)(rp + q * 4);
            }
            float s = 0.f, s2 = 0.f;
#pragma unroll
            for (int ni = 0; ni < 16; ++ni) {
                float v = acc[mi][ni][j] + bv[ni] + rv[ni];
                acc[mi][ni][j] = v;
                s += v; s2 += v * v;
            }
#pragma unroll
            for (int off = 8; off; off >>= 1) {
                s  += __shfl_xor(s,  off, 16);
                s2 += __shfl_xor(s2, off, 16);
            }
            float mu = s * (1.f / 256.f);
            float var = s2 * (1.f / 256.f) - mu * mu;
            mean_[mi][j] = mu;
            rstd_[mi][j] = rsqrtf(var + 1e-5f);
        }

    float gv[16], bev[16];
#pragma unroll
    for (int q = 0; q < 4; ++q) {
        *(float4*)(gv + q * 4)  = *(const float4*)(g + c0 + q * 4);
        *(float4*)(bev + q * 4) = *(const float4*)(be + c0 + q * 4);
    }

#pragma unroll
    for (int mi = 0; mi < 2; ++mi)
#pragma unroll
        for (int j = 0; j < 4; ++j) {
            int rr = bm + wave * 32 + mi * 16 + orow + j;
            if (rr < M) {
                float o[16];
#pragma unroll
                for (int ni = 0; ni < 16; ++ni)
                    o[ni] = (acc[mi][ni][j] - mean_[mi][j]) * rstd_[mi][j] * gv[ni] + bev[ni];
                if (WF32) {
#pragma unroll
                    for (int q = 0; q < 4; ++q)
                        *(float4*)(outF + (size_t)rr * 256 + c0 + q * 4) = *(float4*)(o + q * 4);
                }
                if (WBF16) {
                    uint pk[8];
#pragma unroll
                    for (int b = 0; b < 8; ++b)
                        pk[b] = (unsigned)f2bf(o[2 * b]) | ((unsigned)f2bf(o[2 * b + 1]) << 16);
                    *(uint4*)(outB + (size_t)rr * 256 + c0)     = *(uint4*)pk;
                    *(uint4*)(outB + (size_t)rr * 256 + c0 + 8) = *(uint4*)(pk + 4);
                }
            }
        }
}

// ---------------------------------------------------------------------------
// ALL input conversions in ONE launch.
// ---------------------------------------------------------------------------
struct CvtArgs {
    const float* s[10]; void* d[10]; int n[10]; int isbf[10]; int bcnt[10];
    const float* src; const float* pos; ushort* srcb; ushort* qb;
    int nsrc4; int bsrc;
};
__global__ __launch_bounds__(256) void cvt_all(CvtArgs a)
{
    int b = blockIdx.x;
    if (b < a.bsrc) {
        int i = b * 256 + threadIdx.x;
        if (i >= a.nsrc4) return;
        f32x4v s = *(const f32x4v*)(a.src + (size_t)i * 4);
        f32x4v p = *(const f32x4v*)(a.pos + (size_t)i * 4);
        ushort us[4], uq[4];
#pragma unroll
        for (int j = 0; j < 4; ++j) { us[j] = f2bf(s[j]); uq[j] = f2bf(s[j] + p[j]); }
        *(ulong1*)(a.srcb + (size_t)i * 4) = *(ulong1*)us;
        *(ulong1*)(a.qb   + (size_t)i * 4) = *(ulong1*)uq;
        return;
    }
    b -= a.bsrc;
    int seg = 0;
    while (seg < 9 && b >= a.bcnt[seg]) { b -= a.bcnt[seg]; ++seg; }
    int i = b * 256 + threadIdx.x;
    if (i >= a.n[seg]) return;
    float v = a.s[seg][i];
    if (a.isbf[seg]) ((ushort*)a.d[seg])[i] = f2bf(v);
    else             ((float*)a.d[seg])[i]  = v;
}

// ---------------------------------------------------------------------------
// Deformable attention (round-13 structure: fp16 value, v_pk_fma_f16).
// ---------------------------------------------------------------------------
__global__ __launch_bounds__(256) void deform_kernel(
    const ushort* __restrict__ valh,   // [LQ,256] fp16
    const ushort* __restrict__ qout,   // [LQ,QSTRIDE] bf16: samp|tsamp|logits
    const float* __restrict__ vr,      // [4,2]
    ushort* __restrict__ ob)           // [LQ,256] bf16
{
    const int q0 = blockIdx.x * 2;
    const int tid = threadIdx.x;

    __shared__ int4  offs_s[2][448];
    __shared__ uint2 wts_s[2][448];

    const int lsiA[4] = {0, 18432, 23040, 24192};

    // ---- phase 0: softmax -> staged f32 in wts slot ----
    {
        int grp = tid >> 4;
        int ql = grp >> 3, h = grp & 7;
        int ln = tid & 15;
        const ushort* lg = qout + (size_t)(q0 + ql) * QSTRIDE + 896 + h * 56;
        float l0 = bf2f(lg[ln]);
        float l1 = bf2f(lg[16 + ln]);
        float l2 = bf2f(lg[32 + ln]);
        float l3 = (ln < 8) ? bf2f(lg[48 + ln]) : -1e30f;
        float m = fmaxf(fmaxf(l0, l1), fmaxf(l2, l3));
#pragma unroll
        for (int off = 8; off; off >>= 1) m = fmaxf(m, __shfl_xor(m, off, 16));
        float e0 = expf(l0 - m), e1 = expf(l1 - m), e2 = expf(l2 - m);
        float e3 = (ln < 8) ? expf(l3 - m) : 0.f;
        float s = e0 + e1 + e2 + e3;
#pragma unroll
        for (int off = 8; off; off >>= 1) s += __shfl_xor(s, off, 16);
        float inv = 1.f / s;
        *(float*)&wts_s[ql][h * 56 + ln]      = e0 * inv;
        *(float*)&wts_s[ql][h * 56 + 16 + ln] = e1 * inv;
        *(float*)&wts_s[ql][h * 56 + 32 + ln] = e2 * inv;
        if (ln < 8) *(float*)&wts_s[ql][h * 56 + 48 + ln] = e3 * inv;
    }

    int lqv = (q0 >= 24192) ? 3 : (q0 >= 23040) ? 2 : (q0 >= 18432) ? 1 : 0;
    int Wqv = 64 >> lqv, Hqv = 48 >> lqv;
    int slq = lsiA[lqv];
    float vrxq = vr[2 * lqv], vryq = vr[2 * lqv + 1];
    float rxb0, ryb0, rxb1, ryb1; int tq0, tq1;
    {
        int qi = q0 - slq;
        int iy = qi >> (6 - lqv);
        int jx = qi & (Wqv - 1);
        tq0 = iy / Hqv;
        rxb0 = ((float)jx + 0.5f) / (vrxq * (float)Wqv);
        ryb0 = ((float)iy + 0.5f) / (vryq * (float)(Hqv * 6));
        qi += 1;
        iy = qi >> (6 - lqv);
        jx = qi & (Wqv - 1);
        tq1 = iy / Hqv;
        rxb1 = ((float)jx + 0.5f) / (vrxq * (float)Wqv);
        ryb1 = ((float)iy + 0.5f) / (vryq * (float)(Hqv * 6));
    }
    __syncthreads();

    // ---- phase 1: coords for 2x448 items ----
    for (int it = tid; it < 896; it += 256) {
        int ql = (it >= 448) ? 1 : 0;
        int item = it - ql * 448;
        float rx_base = ql ? rxb1 : rxb0;
        float ry_base = ql ? ryb1 : ryb0;
        int tq = ql ? tq1 : tq0;

        int h = item / 56;
        int p = item - h * 56;
        int l = p / 14;
        int pp = p - l * 14;

        int Wl = 64 >> l;
        int Hl = 48 >> l;
        int Htl = Hl * 6;
        float vrx = vr[2 * l], vry = vr[2 * l + 1];

        float aw = *(const float*)&wts_s[ql][item];

        const ushort* qrow = qout + (size_t)(q0 + ql) * QSTRIDE;
        float ox, oy, ty;
        if (pp < 4) {
            ox = bf2f(qrow[h * 32 + l * 8 + pp * 2]);
            oy = bf2f(qrow[h * 32 + l * 8 + pp * 2 + 1]);
            ty = 0.f;
        } else {
            int pq = pp - 4;
            int tw = pq >> 1, nt = pq & 1;
            int tt = (tw < tq) ? tw : tw + 1;
            ty = (float)(tt - tq) * vry * (float)Hl;
            ox = bf2f(qrow[256 + h * 80 + l * 20 + tw * 4 + nt * 2]);
            oy = bf2f(qrow[256 + h * 80 + l * 20 + tw * 4 + nt * 2 + 1]);
        }
        float x = rx_base * vrx * (float)Wl - 0.5f + ox;
        float y = ry_base * vry * (float)Htl - 0.5f + ty + oy;
        float x0f = floorf(x), y0f = floorf(y);
        int x0 = (int)x0f, y0 = (int)y0f;
        float fx = x - x0f, fy = y - y0f;

        int xi0 = min(max(x0, 0), Wl - 1);
        int xi1 = min(max(x0 + 1, 0), Wl - 1);
        int yi0 = min(max(y0, 0), Htl - 1);
        int yi1 = min(max(y0 + 1, 0), Htl - 1);
        float mx0 = (x0 >= 0 && x0 < Wl) ? 1.f : 0.f;
        float mx1 = (x0 >= -1 && x0 + 1 < Wl) ? 1.f : 0.f;
        float my0 = (y0 >= 0 && y0 < Htl) ? 1.f : 0.f;
        float my1 = (y0 >= -1 && y0 + 1 < Htl) ? 1.f : 0.f;

        float gx0 = (1.f - fx) * mx0;
        float gx1 = fx * mx1;
        float gy0 = (1.f - fy) * my0 * aw;
        float gy1 = fy * my1 * aw;

        int sl = lsiA[l];
        int rb0 = (sl + yi0 * Wl) * 512;
        int rb1 = (sl + yi1 * Wl) * 512;
        offs_s[ql][item] = make_int4(rb0 + xi0 * 512, rb0 + xi1 * 512,
                                     rb1 + xi0 * 512, rb1 + xi1 * 512);
        __half2 hA = __halves2half2(__float2half(gy0 * gx0), __float2half(gy0 * gx1));
        __half2 hB = __halves2half2(__float2half(gy1 * gx0), __float2half(gy1 * gx1));
        wts_s[ql][item] = make_uint2(*(const unsigned*)&hA, *(const unsigned*)&hB);
    }
    __syncthreads();

    // ---- phase 2: 2 channels/thread, dword f16 gathers, v_pk_fma_f16 ----
    const int ql = tid >> 7;
    const int h = (tid >> 4) & 7;
    const int c2 = tid & 15;
    const unsigned laneByte = (unsigned)(h * 64 + c2 * 4);
    const char* vbase = (const char*)valh;
    const int4* op = offs_s[ql] + h * 56;
    const uint2* wp = wts_s[ql] + h * 56;
    unsigned acc = 0;
#pragma unroll 8
    for (int p = 0; p < 56; ++p) {
        int4 o4 = op[p];
        uint2 w2 = wp[p];
        unsigned u0 = *(const unsigned*)(vbase + (size_t)(unsigned)(o4.x + laneByte));
        unsigned u1 = *(const unsigned*)(vbase + (size_t)(unsigned)(o4.y + laneByte));
        unsigned u2 = *(const unsigned*)(vbase + (size_t)(unsigned)(o4.z + laneByte));
        unsigned u3 = *(const unsigned*)(vbase + (size_t)(unsigned)(o4.w + laneByte));
        pkf16_lo(acc, u0, w2.x);
        pkf16_hi(acc, u1, w2.x);
        pkf16_lo(acc, u2, w2.y);
        pkf16_hi(acc, u3, w2.y);
    }
    float2 af = __half22float2(*(const __half2*)&acc);
    unsigned packed = (unsigned)f2bf(af.x) | ((unsigned)f2bf(af.y) << 16);
    *(unsigned*)(ob + (size_t)(q0 + ql) * 256 + h * 32 + c2 * 2) = packed;
}

// ---------------------------------------------------------------------------
extern "C" void kernel_launch(void* const* d_in, const int* in_sizes, int n_in,
                              void* d_out, int out_size, void* d_ws, size_t ws_size,
                              hipStream_t stream)
{
    const float* src    = (const float*)d_in[0];
    const float* pos    = (const float*)d_in[1];
    const float* vr     = (const float*)d_in[4];
    const float* W_samp = (const float*)d_in[5];
    const float* b_samp = (const float*)d_in[6];
    const float* W_tsamp= (const float*)d_in[7];
    const float* b_tsamp= (const float*)d_in[8];
    const float* W_attn = (const float*)d_in[9];
    const float* b_attn = (const float*)d_in[10];
    const float* W_val  = (const float*)d_in[11];
    const float* b_val  = (const float*)d_in[12];
    const float* W_out  = (const float*)d_in[13];
    const float* b_out  = (const float*)d_in[14];
    const float* W_ff1  = (const float*)d_in[15];
    const float* b_ff1  = (const float*)d_in[16];
    const float* W_ff2  = (const float*)d_in[17];
    const float* b_ff2  = (const float*)d_in[18];
    const float* n1g    = (const float*)d_in[19];
    const float* n1b    = (const float*)d_in[20];
    const float* n2g    = (const float*)d_in[21];
    const float* n2b    = (const float*)d_in[22];

    // ---- workspace layout (f32 units) ----
    float* ws = (float*)d_ws;
    ushort* qout  = (ushort*)ws;                         // LQ*1408 bf16
    float* valueR = ws + (size_t)LQ * 704;               // region: LQ*256 f32
    ushort* valh  = (ushort*)valueR;                     // LQ*256 fp16
    ushort* srcb  = (ushort*)(valueR + (size_t)LQ * 256);// LQ*256 bf16
    ushort* qb    = srcb + (size_t)LQ * 256;             // LQ*256 bf16
    ushort* obuf  = qb + (size_t)LQ * 256;               // LQ*256 bf16
    float* ffB    = (float*)(obuf + (size_t)LQ * 256);   // LQ*256 f32 (spacer)
    ushort* Wq    = (ushort*)(ffB + (size_t)LQ * 256);   // 1408*256 bf16 (rows 1344+ garbage)
    ushort* Wv    = Wq + 1408 * 256;
    ushort* Wo    = Wv + 256 * 256;
    ushort* Wf1   = Wo + 256 * 256;
    ushort* Wf2   = Wf1 + 1024 * 256;
    float* bq     = (float*)(Wf2 + 1024 * 256);          // 1408 f32 (tail garbage)
    // region reuse after deform:
    ushort* xB16  = (ushort*)qout;                       // LQ*256 bf16 (qout dead)
    ushort* hB16  = (ushort*)valueR;                     // LQ*1024 bf16 spans valueR..qb

    // ---- input conversions (ONE launch) ----
    CvtArgs ca;
    ca.s[0] = W_samp;  ca.d[0] = Wq;             ca.n[0] = 256 * 256;  ca.isbf[0] = 1;
    ca.s[1] = W_tsamp; ca.d[1] = Wq + 256 * 256; ca.n[1] = 640 * 256;  ca.isbf[1] = 1;
    ca.s[2] = W_attn;  ca.d[2] = Wq + 896 * 256; ca.n[2] = 448 * 256;  ca.isbf[2] = 1;
    ca.s[3] = W_val;   ca.d[3] = Wv;             ca.n[3] = 256 * 256;  ca.isbf[3] = 1;
    ca.s[4] = W_out;   ca.d[4] = Wo;             ca.n[4] = 256 * 256;  ca.isbf[4] = 1;
    ca.s[5] = W_ff1;   ca.d[5] = Wf1;            ca.n[5] = 1024 * 256; ca.isbf[5] = 1;
    ca.s[6] = W_ff2;   ca.d[6] = Wf2;            ca.n[6] = 256 * 1024; ca.isbf[6] = 1;
    ca.s[7] = b_samp;  ca.d[7] = bq;             ca.n[7] = 256;        ca.isbf[7] = 0;
    ca.s[8] = b_tsamp; ca.d[8] = bq + 256;       ca.n[8] = 640;        ca.isbf[8] = 0;
    ca.s[9] = b_attn;  ca.d[9] = bq + 896;       ca.n[9] = 448;        ca.isbf[9] = 0;
    ca.src = src; ca.pos = pos; ca.srcb = srcb; ca.qb = qb;
    ca.nsrc4 = LQ * 64;
    ca.bsrc = (ca.nsrc4 + 255) / 256;
    int total_blocks = ca.bsrc;
    for (int sgi = 0; sgi < 10; ++sgi) {
        ca.bcnt[sgi] = (ca.n[sgi] + 255) / 256;
        total_blocks += ca.bcnt[sgi];
    }
    cvt_all<<<total_blocks, 256, 0, stream>>>(ca);

    const int GM = (LQ + 127) / 128;   // 192

    // fused: value-proj (fp16 out) + q-proj (bf16 out, stride 1408),
    // global_load_lds-staged
    gemm_valq<<<dim3(13, GM), 256, 0, stream>>>(srcb, qb, Wv, Wq, b_val, bq, valh, qout);

    // deformable attention (bf16 out), 2 queries per block
    deform_kernel<<<LQ / 2, 256, 0, stream>>>(valh, qout, vr, obuf);

    // out-proj + residual(src f32) + LN1 -> xB16 (bf16 only)
    gemm_ln<0, 0, 1><<<GM, 256, 0, stream>>>(obuf, Wo, b_out, src, n1g, n1b,
                                             nullptr, xB16, LQ, 256);

    // FFN: ff1 (relu, bf16 out, global_load_lds-staged) ; ff2 + LN2 -> d_out
    gemm_ff1<<<dim3(8, GM), 256, 0, stream>>>(xB16, Wf1, b_ff1, hB16);
    gemm_ln<1, 1, 0><<<GM, 256, 0, stream>>>(hB16, Wf2, b_ff2, xB16, n2g, n2b,
                                             (float*)d_out, nullptr, LQ, 1024);
}

// Round 17
// 275.442 us; speedup vs baseline: 1.2352x; 1.2352x over previous
//
#include <hip/hip_runtime.h>
#include <hip/hip_bf16.h>
#include <hip/hip_fp16.h>
#include <math.h>

#define LQ 24480
#define QSTRIDE 1408   // qout row stride (11 x 128 col-blocks)

typedef short bf16x8 __attribute__((ext_vector_type(8)));   // 8 bf16 = 16B
typedef float f32x4 __attribute__((ext_vector_type(4)));
typedef float f32x4v __attribute__((ext_vector_type(4)));

static __device__ __forceinline__ float bf2f(ushort u) {
    union { unsigned int i; float f; } v; v.i = ((unsigned int)u) << 16; return v.f;
}
static __device__ __forceinline__ ushort f2bf(float f) {
    __hip_bfloat16 h = __float2bfloat16(f);
    return *reinterpret_cast<ushort*>(&h);
}
static __device__ __forceinline__ ushort f2h(float f) {
    __half h = __float2half(f);
    return *reinterpret_cast<ushort*>(&h);
}
static __device__ __forceinline__ float u2f_lo(unsigned int u) {
    union { unsigned int i; float f; } v; v.i = u << 16; return v.f;
}
static __device__ __forceinline__ float u2f_hi(unsigned int u) {
    union { unsigned int i; float f; } v; v.i = u & 0xffff0000u; return v.f;
}
// packed f16 FMA, weight broadcast from lo half of w
static __device__ __forceinline__ void pkf16_lo(unsigned& acc, unsigned v, unsigned w) {
    asm("v_pk_fma_f16 %0, %1, %2, %0 op_sel:[0,0,0] op_sel_hi:[1,0,1]"
        : "+v"(acc) : "v"(v), "v"(w));
}
// weight broadcast from hi half of w
static __device__ __forceinline__ void pkf16_hi(unsigned& acc, unsigned v, unsigned w) {
    asm("v_pk_fma_f16 %0, %1, %2, %0 op_sel:[0,1,0] op_sel_hi:[1,1,1]"
        : "+v"(acc) : "v"(v), "v"(w));
}

// ---------------------------------------------------------------------------
// LDS-staged GEMM body (r14 reg-staged version): block 128x128, BK=32,
// double-buffered global->reg->LDS staging.
// LDS per buffer: [4 kblk][129 slots of 16B] (stride 1032 ushorts).
// A: slot=row. B: slot=(c&3)*32+(c>>2) -> fragment reads lane-consecutive.
// ---------------------------------------------------------------------------
template <int RELU, int F16OUT>
static __device__ __forceinline__ void gemm_lds128(
    const ushort* __restrict__ A, const ushort* __restrict__ W,
    const float* __restrict__ bias, ushort* __restrict__ Cb,
    int M, int N, int K, int bm, int bn,
    ushort* As, ushort* Bs, int tid)
{
    const int wave = tid >> 6, lane = tid & 63;
    const int wm = wave >> 1, wn = wave & 1;
    const int r = lane & 15, kblk4 = lane >> 4;

    const int skb = tid & 3;
    const int sr0 = tid >> 2;           // 0..63
    const ushort* gA0 = A + (size_t)min(bm + sr0,      M - 1) * K + skb * 8;
    const ushort* gA1 = A + (size_t)min(bm + 64 + sr0, M - 1) * K + skb * 8;
    const ushort* gB0 = W + (size_t)(bn + sr0) * K + skb * 8;
    const ushort* gB1 = W + (size_t)(bn + 64 + sr0) * K + skb * 8;
    const int wA0 = skb * 1032 + sr0 * 8;
    const int wA1 = skb * 1032 + (64 + sr0) * 8;
    const int wB0 = skb * 1032 + ((sr0 & 3) * 32 + (sr0 >> 2)) * 8;
    const int wB1 = skb * 1032 + (((64 + sr0) & 3) * 32 + ((64 + sr0) >> 2)) * 8;

    f32x4 acc[4][4] = {};

    bf16x8 ga0 = *(const bf16x8*)gA0;
    bf16x8 ga1 = *(const bf16x8*)gA1;
    bf16x8 gb0 = *(const bf16x8*)gB0;
    bf16x8 gb1 = *(const bf16x8*)gB1;
    *(bf16x8*)(As + wA0) = ga0;
    *(bf16x8*)(As + wA1) = ga1;
    *(bf16x8*)(Bs + wB0) = gb0;
    *(bf16x8*)(Bs + wB1) = gb1;

    const int NK = K >> 5;
    int buf = 0;
    for (int kt = 0; kt < NK; ++kt) {
        __syncthreads();
        if (kt + 1 < NK) {
            int ko = (kt + 1) * 32;
            ga0 = *(const bf16x8*)(gA0 + ko);
            ga1 = *(const bf16x8*)(gA1 + ko);
            gb0 = *(const bf16x8*)(gB0 + ko);
            gb1 = *(const bf16x8*)(gB1 + ko);
        }
        const ushort* Ab = As + buf * 4128;
        const ushort* Bb = Bs + buf * 4128;
        bf16x8 a[4], b[4];
#pragma unroll
        for (int i = 0; i < 4; ++i)
            a[i] = *(const bf16x8*)(Ab + kblk4 * 1032 + (wm * 64 + i * 16 + r) * 8);
#pragma unroll
        for (int j = 0; j < 4; ++j)
            b[j] = *(const bf16x8*)(Bb + kblk4 * 1032 + (j * 32 + wn * 16 + r) * 8);
#pragma unroll
        for (int i = 0; i < 4; ++i)
#pragma unroll
            for (int j = 0; j < 4; ++j)
                acc[i][j] = __builtin_amdgcn_mfma_f32_16x16x32_bf16(a[i], b[j], acc[i][j], 0, 0, 0);
        if (kt + 1 < NK) {
            ushort* An = As + (buf ^ 1) * 4128;
            ushort* Bn = Bs + (buf ^ 1) * 4128;
            *(bf16x8*)(An + wA0) = ga0;
            *(bf16x8*)(An + wA1) = ga1;
            *(bf16x8*)(Bn + wB0) = gb0;
            *(bf16x8*)(Bn + wB1) = gb1;
        }
        buf ^= 1;
    }

    const int c0 = bn + wn * 64 + r * 4;
    if (c0 >= N) return;
    const float4 bv = *(const float4*)(bias + c0);
    const int orow = kblk4 * 4;
#pragma unroll
    for (int i = 0; i < 4; ++i)
#pragma unroll
        for (int t = 0; t < 4; ++t) {
            int rr = bm + wm * 64 + i * 16 + orow + t;
            if (rr < M) {
                float v0 = acc[i][0][t] + bv.x;
                float v1 = acc[i][1][t] + bv.y;
                float v2 = acc[i][2][t] + bv.z;
                float v3 = acc[i][3][t] + bv.w;
                if (RELU) {
                    v0 = fmaxf(v0, 0.f); v1 = fmaxf(v1, 0.f);
                    v2 = fmaxf(v2, 0.f); v3 = fmaxf(v3, 0.f);
                }
                uint2 pk;
                if (F16OUT) {
                    pk.x = (unsigned)f2h(v0) | ((unsigned)f2h(v1) << 16);
                    pk.y = (unsigned)f2h(v2) | ((unsigned)f2h(v3) << 16);
                } else {
                    pk.x = (unsigned)f2bf(v0) | ((unsigned)f2bf(v1) << 16);
                    pk.y = (unsigned)f2bf(v2) | ((unsigned)f2bf(v3) << 16);
                }
                *(uint2*)(Cb + (size_t)rr * N + c0) = pk;
            }
        }
}

// Fused value-proj (fp16 out, N=256) + q-proj (bf16 out, N=1408 padded).
__global__ __launch_bounds__(256) void gemm_valq(
    const ushort* __restrict__ srcb, const ushort* __restrict__ qb,
    const ushort* __restrict__ Wv, const ushort* __restrict__ Wq,
    const float* __restrict__ b_val, const float* __restrict__ bq,
    ushort* __restrict__ valh, ushort* __restrict__ qout)
{
    __shared__ ushort As[2 * 4128];
    __shared__ ushort Bs[2 * 4128];
    const int bx = blockIdx.x;   // 0..12
    if (bx < 2) {
        gemm_lds128<0, 1>(srcb, Wv, b_val, valh, LQ, 256, 256,
                          blockIdx.y * 128, bx * 128, As, Bs, threadIdx.x);
    } else {
        gemm_lds128<0, 0>(qb, Wq, bq, qout, LQ, QSTRIDE, 256,
                          blockIdx.y * 128, (bx - 2) * 128, As, Bs, threadIdx.x);
    }
}

// ff1: relu, bf16 out, N=1024
__global__ __launch_bounds__(256) void gemm_ff1(
    const ushort* __restrict__ A, const ushort* __restrict__ W,
    const float* __restrict__ bias, ushort* __restrict__ Cb)
{
    __shared__ ushort As[2 * 4128];
    __shared__ ushort Bs[2 * 4128];
    gemm_lds128<1, 0>(A, W, bias, Cb, LQ, 1024, 256,
                      blockIdx.y * 128, blockIdx.x * 128, As, Bs, threadIdx.x);
}

// ---------------------------------------------------------------------------
// Fused GEMM (N=256) + residual + LayerNorm, now LDS-staged (BK=32, dbuf).
// A tile 128x32 in [4 kblk][129x16B]; B tile 256x32 in [4 kblk][257x16B],
// B slot = ((c&15)<<4)|(c>>4) so the ni*16+r fragment read is
// lane-consecutive. Epilogue unchanged (thread owns 16 consecutive cols).
// ---------------------------------------------------------------------------
template <int RES16, int WF32, int WBF16>
__global__ __launch_bounds__(256) void gemm_ln(
    const ushort* __restrict__ A, const ushort* __restrict__ W,
    const float* __restrict__ bias, const void* __restrict__ res,
    const float* __restrict__ g, const float* __restrict__ be,
    float* __restrict__ outF, ushort* __restrict__ outB,
    int M, int K)
{
    __shared__ ushort As[2 * 4128];    // 4 kblk x 129 slots x 8
    __shared__ ushort Bs[2 * 8224];    // 4 kblk x 257 slots x 8
    const int tid = threadIdx.x;
    const int wave = tid >> 6;
    const int lane = tid & 63;
    const int r = lane & 15;
    const int kblk4 = lane >> 4;
    const int bm = blockIdx.x * 128;
    const int c0 = r * 16;

    // staging assignment
    const int skb = tid & 3;
    const int sr0 = tid >> 2;          // 0..63
    const ushort* gA0 = A + (size_t)min(bm + sr0,      M - 1) * K + skb * 8;
    const ushort* gA1 = A + (size_t)min(bm + 64 + sr0, M - 1) * K + skb * 8;
    const int wA0 = skb * 1032 + sr0 * 8;
    const int wA1 = skb * 1032 + (64 + sr0) * 8;
    const ushort* gBp[4]; int wBp[4];
#pragma unroll
    for (int i = 0; i < 4; ++i) {
        int cc = sr0 + 64 * i;
        gBp[i] = W + (size_t)cc * K + skb * 8;
        wBp[i] = skb * 2056 + ((((cc) & 15) << 4) | ((cc) >> 4)) * 8;
    }

    f32x4 acc[2][16] = {};

    // prologue: stage k-step 0
    bf16x8 ga0 = *(const bf16x8*)gA0;
    bf16x8 ga1 = *(const bf16x8*)gA1;
    bf16x8 gb[4];
#pragma unroll
    for (int i = 0; i < 4; ++i) gb[i] = *(const bf16x8*)gBp[i];
    *(bf16x8*)(As + wA0) = ga0;
    *(bf16x8*)(As + wA1) = ga1;
#pragma unroll
    for (int i = 0; i < 4; ++i) *(bf16x8*)(Bs + wBp[i]) = gb[i];

    const int NK = K >> 5;
    int buf = 0;
    for (int kt = 0; kt < NK; ++kt) {
        __syncthreads();
        if (kt + 1 < NK) {
            int ko = (kt + 1) * 32;
            ga0 = *(const bf16x8*)(gA0 + ko);
            ga1 = *(const bf16x8*)(gA1 + ko);
#pragma unroll
            for (int i = 0; i < 4; ++i) gb[i] = *(const bf16x8*)(gBp[i] + ko);
        }
        const ushort* Ab = As + buf * 4128;
        const ushort* Bb = Bs + buf * 8224;
        bf16x8 a0 = *(const bf16x8*)(Ab + kblk4 * 1032 + (wave * 32 + r) * 8);
        bf16x8 a1 = *(const bf16x8*)(Ab + kblk4 * 1032 + (wave * 32 + 16 + r) * 8);
#pragma unroll
        for (int ni = 0; ni < 16; ++ni) {
            bf16x8 b = *(const bf16x8*)(Bb + kblk4 * 2056 + (ni * 16 + r) * 8);
            acc[0][ni] = __builtin_amdgcn_mfma_f32_16x16x32_bf16(a0, b, acc[0][ni], 0, 0, 0);
            acc[1][ni] = __builtin_amdgcn_mfma_f32_16x16x32_bf16(a1, b, acc[1][ni], 0, 0, 0);
        }
        if (kt + 1 < NK) {
            ushort* An = As + (buf ^ 1) * 4128;
            ushort* Bn = Bs + (buf ^ 1) * 8224;
            *(bf16x8*)(An + wA0) = ga0;
            *(bf16x8*)(An + wA1) = ga1;
#pragma unroll
            for (int i = 0; i < 4; ++i) *(bf16x8*)(Bn + wBp[i]) = gb[i];
        }
        buf ^= 1;
    }

    const int orow = kblk4 * 4;

    float bv[16];
#pragma unroll
    for (int q = 0; q < 4; ++q)
        *(float4*)(bv + q * 4) = *(const float4*)(bias + c0 + q * 4);

    float mean_[2][4], rstd_[2][4];
#pragma unroll
    for (int mi = 0; mi < 2; ++mi)
#pragma unroll
        for (int j = 0; j < 4; ++j) {
            int rr = bm + wave * 32 + mi * 16 + orow + j;
            int rl = min(rr, M - 1);
            float rv[16];
            if (RES16) {
                const ushort* r16 = (const ushort*)res + (size_t)rl * 256 + c0;
                uint4 ra = *(const uint4*)r16;
                uint4 rb = *(const uint4*)(r16 + 8);
                unsigned ru[8] = {ra.x, ra.y, ra.z, ra.w, rb.x, rb.y, rb.z, rb.w};
#pragma unroll
                for (int b = 0; b < 8; ++b) {
                    rv[2 * b]     = u2f_lo(ru[b]);
                    rv[2 * b + 1] = u2f_hi(ru[b]);
                }
            } else {
                const float* rp = (const float*)res + (size_t)rl * 256 + c0;
#pragma unroll
                for (int q = 0; q < 4; ++q)
                    *(float4*)(rv + q * 4) = *(const float4*)(rp + q * 4);
            }
            float s = 0.f, s2 = 0.f;
#pragma unroll
            for (int ni = 0; ni < 16; ++ni) {
                float v = acc[mi][ni][j] + bv[ni] + rv[ni];
                acc[mi][ni][j] = v;
                s += v; s2 += v * v;
            }
#pragma unroll
            for (int off = 8; off; off >>= 1) {
                s  += __shfl_xor(s,  off, 16);
                s2 += __shfl_xor(s2, off, 16);
            }
            float mu = s * (1.f / 256.f);
            float var = s2 * (1.f / 256.f) - mu * mu;
            mean_[mi][j] = mu;
            rstd_[mi][j] = rsqrtf(var + 1e-5f);
        }

    float gv[16], bev[16];
#pragma unroll
    for (int q = 0; q < 4; ++q) {
        *(float4*)(gv + q * 4)  = *(const float4*)(g + c0 + q * 4);
        *(float4*)(bev + q * 4) = *(const float4*)(be + c0 + q * 4);
    }

#pragma unroll
    for (int mi = 0; mi < 2; ++mi)
#pragma unroll
        for (int j = 0; j < 4; ++j) {
            int rr = bm + wave * 32 + mi * 16 + orow + j;
            if (rr < M) {
                float o[16];
#pragma unroll
                for (int ni = 0; ni < 16; ++ni)
                    o[ni] = (acc[mi][ni][j] - mean_[mi][j]) * rstd_[mi][j] * gv[ni] + bev[ni];
                if (WF32) {
#pragma unroll
                    for (int q = 0; q < 4; ++q)
                        *(float4*)(outF + (size_t)rr * 256 + c0 + q * 4) = *(float4*)(o + q * 4);
                }
                if (WBF16) {
                    uint pk[8];
#pragma unroll
                    for (int b = 0; b < 8; ++b)
                        pk[b] = (unsigned)f2bf(o[2 * b]) | ((unsigned)f2bf(o[2 * b + 1]) << 16);
                    *(uint4*)(outB + (size_t)rr * 256 + c0)     = *(uint4*)pk;
                    *(uint4*)(outB + (size_t)rr * 256 + c0 + 8) = *(uint4*)(pk + 4);
                }
            }
        }
}

// ---------------------------------------------------------------------------
// ALL input conversions in ONE launch.
// ---------------------------------------------------------------------------
struct CvtArgs {
    const float* s[10]; void* d[10]; int n[10]; int isbf[10]; int bcnt[10];
    const float* src; const float* pos; ushort* srcb; ushort* qb;
    int nsrc4; int bsrc;
};
__global__ __launch_bounds__(256) void cvt_all(CvtArgs a)
{
    int b = blockIdx.x;
    if (b < a.bsrc) {
        int i = b * 256 + threadIdx.x;
        if (i >= a.nsrc4) return;
        f32x4v s = *(const f32x4v*)(a.src + (size_t)i * 4);
        f32x4v p = *(const f32x4v*)(a.pos + (size_t)i * 4);
        ushort us[4], uq[4];
#pragma unroll
        for (int j = 0; j < 4; ++j) { us[j] = f2bf(s[j]); uq[j] = f2bf(s[j] + p[j]); }
        *(ulong1*)(a.srcb + (size_t)i * 4) = *(ulong1*)us;
        *(ulong1*)(a.qb   + (size_t)i * 4) = *(ulong1*)uq;
        return;
    }
    b -= a.bsrc;
    int seg = 0;
    while (seg < 9 && b >= a.bcnt[seg]) { b -= a.bcnt[seg]; ++seg; }
    int i = b * 256 + threadIdx.x;
    if (i >= a.n[seg]) return;
    float v = a.s[seg][i];
    if (a.isbf[seg]) ((ushort*)a.d[seg])[i] = f2bf(v);
    else             ((float*)a.d[seg])[i]  = v;
}

// ---------------------------------------------------------------------------
// Deformable attention (round-13 structure: fp16 value, v_pk_fma_f16).
// ---------------------------------------------------------------------------
__global__ __launch_bounds__(256) void deform_kernel(
    const ushort* __restrict__ valh,   // [LQ,256] fp16
    const ushort* __restrict__ qout,   // [LQ,QSTRIDE] bf16: samp|tsamp|logits
    const float* __restrict__ vr,      // [4,2]
    ushort* __restrict__ ob)           // [LQ,256] bf16
{
    const int q0 = blockIdx.x * 2;
    const int tid = threadIdx.x;

    __shared__ int4  offs_s[2][448];
    __shared__ uint2 wts_s[2][448];

    const int lsiA[4] = {0, 18432, 23040, 24192};

    // ---- phase 0: softmax -> staged f32 in wts slot ----
    {
        int grp = tid >> 4;
        int ql = grp >> 3, h = grp & 7;
        int ln = tid & 15;
        const ushort* lg = qout + (size_t)(q0 + ql) * QSTRIDE + 896 + h * 56;
        float l0 = bf2f(lg[ln]);
        float l1 = bf2f(lg[16 + ln]);
        float l2 = bf2f(lg[32 + ln]);
        float l3 = (ln < 8) ? bf2f(lg[48 + ln]) : -1e30f;
        float m = fmaxf(fmaxf(l0, l1), fmaxf(l2, l3));
#pragma unroll
        for (int off = 8; off; off >>= 1) m = fmaxf(m, __shfl_xor(m, off, 16));
        float e0 = expf(l0 - m), e1 = expf(l1 - m), e2 = expf(l2 - m);
        float e3 = (ln < 8) ? expf(l3 - m) : 0.f;
        float s = e0 + e1 + e2 + e3;
#pragma unroll
        for (int off = 8; off; off >>= 1) s += __shfl_xor(s, off, 16);
        float inv = 1.f / s;
        *(float*)&wts_s[ql][h * 56 + ln]      = e0 * inv;
        *(float*)&wts_s[ql][h * 56 + 16 + ln] = e1 * inv;
        *(float*)&wts_s[ql][h * 56 + 32 + ln] = e2 * inv;
        if (ln < 8) *(float*)&wts_s[ql][h * 56 + 48 + ln] = e3 * inv;
    }

    int lqv = (q0 >= 24192) ? 3 : (q0 >= 23040) ? 2 : (q0 >= 18432) ? 1 : 0;
    int Wqv = 64 >> lqv, Hqv = 48 >> lqv;
    int slq = lsiA[lqv];
    float vrxq = vr[2 * lqv], vryq = vr[2 * lqv + 1];
    float rxb0, ryb0, rxb1, ryb1; int tq0, tq1;
    {
        int qi = q0 - slq;
        int iy = qi >> (6 - lqv);
        int jx = qi & (Wqv - 1);
        tq0 = iy / Hqv;
        rxb0 = ((float)jx + 0.5f) / (vrxq * (float)Wqv);
        ryb0 = ((float)iy + 0.5f) / (vryq * (float)(Hqv * 6));
        qi += 1;
        iy = qi >> (6 - lqv);
        jx = qi & (Wqv - 1);
        tq1 = iy / Hqv;
        rxb1 = ((float)jx + 0.5f) / (vrxq * (float)Wqv);
        ryb1 = ((float)iy + 0.5f) / (vryq * (float)(Hqv * 6));
    }
    __syncthreads();

    // ---- phase 1: coords for 2x448 items ----
    for (int it = tid; it < 896; it += 256) {
        int ql = (it >= 448) ? 1 : 0;
        int item = it - ql * 448;
        float rx_base = ql ? rxb1 : rxb0;
        float ry_base = ql ? ryb1 : ryb0;
        int tq = ql ? tq1 : tq0;

        int h = item / 56;
        int p = item - h * 56;
        int l = p / 14;
        int pp = p - l * 14;

        int Wl = 64 >> l;
        int Hl = 48 >> l;
        int Htl = Hl * 6;
        float vrx = vr[2 * l], vry = vr[2 * l + 1];

        float aw = *(const float*)&wts_s[ql][item];

        const ushort* qrow = qout + (size_t)(q0 + ql) * QSTRIDE;
        float ox, oy, ty;
        if (pp < 4) {
            ox = bf2f(qrow[h * 32 + l * 8 + pp * 2]);
            oy = bf2f(qrow[h * 32 + l * 8 + pp * 2 + 1]);
            ty = 0.f;
        } else {
            int pq = pp - 4;
            int tw = pq >> 1, nt = pq & 1;
            int tt = (tw < tq) ? tw : tw + 1;
            ty = (float)(tt - tq) * vry * (float)Hl;
            ox = bf2f(qrow[256 + h * 80 + l * 20 + tw * 4 + nt * 2]);
            oy = bf2f(qrow[256 + h * 80 + l * 20 + tw * 4 + nt * 2 + 1]);
        }
        float x = rx_base * vrx * (float)Wl - 0.5f + ox;
        float y = ry_base * vry * (float)Htl - 0.5f + ty + oy;
        float x0f = floorf(x), y0f = floorf(y);
        int x0 = (int)x0f, y0 = (int)y0f;
        float fx = x - x0f, fy = y - y0f;

        int xi0 = min(max(x0, 0), Wl - 1);
        int xi1 = min(max(x0 + 1, 0), Wl - 1);
        int yi0 = min(max(y0, 0), Htl - 1);
        int yi1 = min(max(y0 + 1, 0), Htl - 1);
        float mx0 = (x0 >= 0 && x0 < Wl) ? 1.f : 0.f;
        float mx1 = (x0 >= -1 && x0 + 1 < Wl) ? 1.f : 0.f;
        float my0 = (y0 >= 0 && y0 < Htl) ? 1.f : 0.f;
        float my1 = (y0 >= -1 && y0 + 1 < Htl) ? 1.f : 0.f;

        float gx0 = (1.f - fx) * mx0;
        float gx1 = fx * mx1;
        float gy0 = (1.f - fy) * my0 * aw;
        float gy1 = fy * my1 * aw;

        int sl = lsiA[l];
        int rb0 = (sl + yi0 * Wl) * 512;
        int rb1 = (sl + yi1 * Wl) * 512;
        offs_s[ql][item] = make_int4(rb0 + xi0 * 512, rb0 + xi1 * 512,
                                     rb1 + xi0 * 512, rb1 + xi1 * 512);
        __half2 hA = __halves2half2(__float2half(gy0 * gx0), __float2half(gy0 * gx1));
        __half2 hB = __halves2half2(__float2half(gy1 * gx0), __float2half(gy1 * gx1));
        wts_s[ql][item] = make_uint2(*(const unsigned*)&hA, *(const unsigned*)&hB);
    }
    __syncthreads();

    // ---- phase 2: 2 channels/thread, dword f16 gathers, v_pk_fma_f16 ----
    const int ql = tid >> 7;
    const int h = (tid >> 4) & 7;
    const int c2 = tid & 15;
    const unsigned laneByte = (unsigned)(h * 64 + c2 * 4);
    const char* vbase = (const char*)valh;
    const int4* op = offs_s[ql] + h * 56;
    const uint2* wp = wts_s[ql] + h * 56;
    unsigned acc = 0;
#pragma unroll 8
    for (int p = 0; p < 56; ++p) {
        int4 o4 = op[p];
        uint2 w2 = wp[p];
        unsigned u0 = *(const unsigned*)(vbase + (size_t)(unsigned)(o4.x + laneByte));
        unsigned u1 = *(const unsigned*)(vbase + (size_t)(unsigned)(o4.y + laneByte));
        unsigned u2 = *(const unsigned*)(vbase + (size_t)(unsigned)(o4.z + laneByte));
        unsigned u3 = *(const unsigned*)(vbase + (size_t)(unsigned)(o4.w + laneByte));
        pkf16_lo(acc, u0, w2.x);
        pkf16_hi(acc, u1, w2.x);
        pkf16_lo(acc, u2, w2.y);
        pkf16_hi(acc, u3, w2.y);
    }
    float2 af = __half22float2(*(const __half2*)&acc);
    unsigned packed = (unsigned)f2bf(af.x) | ((unsigned)f2bf(af.y) << 16);
    *(unsigned*)(ob + (size_t)(q0 + ql) * 256 + h * 32 + c2 * 2) = packed;
}

// ---------------------------------------------------------------------------
extern "C" void kernel_launch(void* const* d_in, const int* in_sizes, int n_in,
                              void* d_out, int out_size, void* d_ws, size_t ws_size,
                              hipStream_t stream)
{
    const float* src    = (const float*)d_in[0];
    const float* pos    = (const float*)d_in[1];
    const float* vr     = (const float*)d_in[4];
    const float* W_samp = (const float*)d_in[5];
    const float* b_samp = (const float*)d_in[6];
    const float* W_tsamp= (const float*)d_in[7];
    const float* b_tsamp= (const float*)d_in[8];
    const float* W_attn = (const float*)d_in[9];
    const float* b_attn = (const float*)d_in[10];
    const float* W_val  = (const float*)d_in[11];
    const float* b_val  = (const float*)d_in[12];
    const float* W_out  = (const float*)d_in[13];
    const float* b_out  = (const float*)d_in[14];
    const float* W_ff1  = (const float*)d_in[15];
    const float* b_ff1  = (const float*)d_in[16];
    const float* W_ff2  = (const float*)d_in[17];
    const float* b_ff2  = (const float*)d_in[18];
    const float* n1g    = (const float*)d_in[19];
    const float* n1b    = (const float*)d_in[20];
    const float* n2g    = (const float*)d_in[21];
    const float* n2b    = (const float*)d_in[22];

    // ---- workspace layout (f32 units) ----
    float* ws = (float*)d_ws;
    ushort* qout  = (ushort*)ws;                         // LQ*1408 bf16
    float* valueR = ws + (size_t)LQ * 704;               // region: LQ*256 f32
    ushort* valh  = (ushort*)valueR;                     // LQ*256 fp16
    ushort* srcb  = (ushort*)(valueR + (size_t)LQ * 256);// LQ*256 bf16
    ushort* qb    = srcb + (size_t)LQ * 256;             // LQ*256 bf16
    ushort* obuf  = qb + (size_t)LQ * 256;               // LQ*256 bf16
    float* ffB    = (float*)(obuf + (size_t)LQ * 256);   // LQ*256 f32 (spacer)
    ushort* Wq    = (ushort*)(ffB + (size_t)LQ * 256);   // 1408*256 bf16 (rows 1344+ garbage)
    ushort* Wv    = Wq + 1408 * 256;
    ushort* Wo    = Wv + 256 * 256;
    ushort* Wf1   = Wo + 256 * 256;
    ushort* Wf2   = Wf1 + 1024 * 256;
    float* bq     = (float*)(Wf2 + 1024 * 256);          // 1408 f32 (tail garbage)
    // region reuse after deform:
    ushort* xB16  = (ushort*)qout;                       // LQ*256 bf16 (qout dead)
    ushort* hB16  = (ushort*)valueR;                     // LQ*1024 bf16 spans valueR..qb

    // ---- input conversions (ONE launch) ----
    CvtArgs ca;
    ca.s[0] = W_samp;  ca.d[0] = Wq;             ca.n[0] = 256 * 256;  ca.isbf[0] = 1;
    ca.s[1] = W_tsamp; ca.d[1] = Wq + 256 * 256; ca.n[1] = 640 * 256;  ca.isbf[1] = 1;
    ca.s[2] = W_attn;  ca.d[2] = Wq + 896 * 256; ca.n[2] = 448 * 256;  ca.isbf[2] = 1;
    ca.s[3] = W_val;   ca.d[3] = Wv;             ca.n[3] = 256 * 256;  ca.isbf[3] = 1;
    ca.s[4] = W_out;   ca.d[4] = Wo;             ca.n[4] = 256 * 256;  ca.isbf[4] = 1;
    ca.s[5] = W_ff1;   ca.d[5] = Wf1;            ca.n[5] = 1024 * 256; ca.isbf[5] = 1;
    ca.s[6] = W_ff2;   ca.d[6] = Wf2;            ca.n[6] = 256 * 1024; ca.isbf[6] = 1;
    ca.s[7] = b_samp;  ca.d[7] = bq;             ca.n[7] = 256;        ca.isbf[7] = 0;
    ca.s[8] = b_tsamp; ca.d[8] = bq + 256;       ca.n[8] = 640;        ca.isbf[8] = 0;
    ca.s[9] = b_attn;  ca.d[9] = bq + 896;       ca.n[9] = 448;        ca.isbf[9] = 0;
    ca.src = src; ca.pos = pos; ca.srcb = srcb; ca.qb = qb;
    ca.nsrc4 = LQ * 64;
    ca.bsrc = (ca.nsrc4 + 255) / 256;
    int total_blocks = ca.bsrc;
    for (int sgi = 0; sgi < 10; ++sgi) {
        ca.bcnt[sgi] = (ca.n[sgi] + 255) / 256;
        total_blocks += ca.bcnt[sgi];
    }
    cvt_all<<<total_blocks, 256, 0, stream>>>(ca);

    const int GM = (LQ + 127) / 128;   // 192

    // fused: value-proj (fp16 out) + q-proj (bf16 out, stride 1408), reg-staged
    gemm_valq<<<dim3(13, GM), 256, 0, stream>>>(srcb, qb, Wv, Wq, b_val, bq, valh, qout);

    // deformable attention (bf16 out), 2 queries per block
    deform_kernel<<<LQ / 2, 256, 0, stream>>>(valh, qout, vr, obuf);

    // out-proj + residual(src f32) + LN1 -> xB16 (bf16 only), LDS-staged
    gemm_ln<0, 0, 1><<<GM, 256, 0, stream>>>(obuf, Wo, b_out, src, n1g, n1b,
                                             nullptr, xB16, LQ, 256);

    // FFN: ff1 (relu, bf16 out, reg-staged) ; ff2 + LN2 (LDS-staged) -> d_out
    gemm_ff1<<<dim3(8, GM), 256, 0, stream>>>(xB16, Wf1, b_ff1, hB16);
    gemm_ln<1, 1, 0><<<GM, 256, 0, stream>>>(hB16, Wf2, b_ff2, xB16, n2g, n2b,
                                             (float*)d_out, nullptr, LQ, 1024);
}